// Round 12
// baseline (288.149 us; speedup 1.0000x reference)
//
#include <hip/hip_runtime.h>
#include <cstdint>
#include <cstddef>

#define NPTS 16384
#define KSEL 4096
#define HIDDEN 128
#define NHEADS 8
#define DHEAD 16
#define OUTD 256
#define NSLICE 4   // k/q slices for attn partials
#define FCAP 262144
#define LCAP 2048
#define TAU 0.15f
#define HROW 264   // LDS row stride (shorts) for packed h: non-pow2, 16B-multiple

typedef __attribute__((ext_vector_type(8))) short bf16x8;
typedef __attribute__((ext_vector_type(4))) float f32x4;
typedef __attribute__((ext_vector_type(16))) float f32x16;

#if defined(__has_builtin)
#if __has_builtin(__builtin_amdgcn_exp2f)
#define E2(x) __builtin_amdgcn_exp2f(x)
#endif
#endif
#ifndef E2
#define E2(x) exp2f(x)
#endif

// ---- workspace layout (bytes) ----
constexpr size_t OFF_PA    = 1024;                         // NPTS*16 bf16 (A-side packed)
constexpr size_t OFF_PB    = OFF_PA  + (size_t)NPTS*32;    // NPTS*16 bf16 (B-side packed)
constexpr size_t OFF_SQ    = OFF_PB  + (size_t)NPTS*32;
constexpr size_t OFF_DL    = OFF_SQ  + (size_t)NPTS*4;
constexpr size_t OFF_CNT   = OFF_DL  + (size_t)NPTS*4;     // int (zeroed by k_prep)
constexpr size_t OFF_NFLAG = OFF_CNT + (size_t)NPTS*4;     // uint (zeroed by k_prep)
constexpr size_t OFF_FLG   = OFF_NFLAG + 1024;             // FCAP uints (group flags)
constexpr size_t OFF_SEL   = OFF_FLG + (size_t)FCAP*4;     // KSEL int
constexpr size_t SZ_PK     = (size_t)NHEADS*KSEL*32*2;     // 2 MB packed [hi16|lo16] bf16
constexpr size_t OFF_QPK   = OFF_SEL + (size_t)KSEL*4;
constexpr size_t OFF_KPK   = OFF_QPK + SZ_PK;
constexpr size_t OFF_V     = OFF_KPK + SZ_PK;                      // KSEL*128 f32
constexpr size_t OFF_LP    = OFF_V  + (size_t)KSEL*HIDDEN*4;       // 8*4096*4 f32 partial l
constexpr size_t OFF_WP    = OFF_LP + (size_t)NHEADS*KSEL*NSLICE*4; // 8*4096*4 f32 partial w
constexpr size_t OFF_PAV   = OFF_WP + (size_t)NHEADS*KSEL*NSLICE*4; // 128 f32
constexpr size_t OFF_WSP   = OFF_PAV + 1024;               // 3*128*256 shorts (split W, B-frag layout)

__device__ __forceinline__ unsigned short f2bf(float f) {
    union { float f; unsigned u; } v; v.f = f;
    unsigned r = v.u + 0x7fffu + ((v.u >> 16) & 1u);
    return (unsigned short)(r >> 16);
}
__device__ __forceinline__ float bf2f(unsigned short h) {
    union { unsigned u; float f; } v; v.u = ((unsigned)h) << 16;
    return v.f;
}

// ---- 1. prep: center, sq, d_lig, packed hi/lo coords; zeroes cnt/nflag/pav ----
__global__ void __launch_bounds__(256) k_prep(const float* __restrict__ pos, const float* __restrict__ lig, int M,
                       unsigned short* __restrict__ pa, unsigned short* __restrict__ pb,
                       float* __restrict__ sq, float* __restrict__ dl,
                       int* __restrict__ cnt, unsigned int* __restrict__ nflag, float* __restrict__ pav) {
    __shared__ float ls[128];
    __shared__ float ctr[3];
    int tid = threadIdx.x;
    int i = blockIdx.x * 256 + tid;
    cnt[i] = 0;
    if (i == 0) *nflag = 0;
    if (blockIdx.x == 0 && tid < HIDDEN) pav[tid] = 0.f;
    for (int k = tid; k < 3 * M; k += 256) ls[k] = lig[k];
    __syncthreads();
    if (tid < 3) {
        float s = 0.f;
        for (int k = 0; k < M; k++) s += ls[k * 3 + tid];
        ctr[tid] = s / (float)M;
    }
    __syncthreads();
    float x = pos[i*3+0], y = pos[i*3+1], z = pos[i*3+2];
    float s = (x*x + y*y) + z*z;
    sq[i] = s;
    float dx = x - ctr[0], dy = y - ctr[1], dz = z - ctr[2];
    dl[i] = sqrtf((dx*dx + dy*dy) + dz*dz);
    unsigned short xh = f2bf(x); float xr = bf2f(xh); float xl = x - xr;
    unsigned short yh = f2bf(y); float yr = bf2f(yh); float yl = y - yr;
    unsigned short zh = f2bf(z); float zr = bf2f(zh); float zl = z - zr;
    unsigned short xlb = f2bf(xl), ylb = f2bf(yl), zlb = f2bf(zl);
    unsigned short xhA = f2bf(-2.f*xr), xlA = f2bf(-2.f*xl);
    unsigned short yhA = f2bf(-2.f*yr), ylA = f2bf(-2.f*yl);
    unsigned short zhA = f2bf(-2.f*zr), zlA = f2bf(-2.f*zl);
    unsigned short sih = f2bf(s);
    unsigned short sil = f2bf(s - bf2f(sih));
    unsigned short one = f2bf(1.0f);
    union { unsigned short s[16]; float4 f[2]; } A, B;
    A.s[0]=xhA; A.s[1]=xhA; A.s[2]=xlA;
    A.s[3]=yhA; A.s[4]=yhA; A.s[5]=ylA;
    A.s[6]=zhA; A.s[7]=zhA; A.s[8]=zlA;
    A.s[9]=xlA; A.s[10]=ylA; A.s[11]=zlA;
    A.s[12]=sih; A.s[13]=sil; A.s[14]=one; A.s[15]=one;
    B.s[0]=xh;  B.s[1]=xlb;  B.s[2]=xh;
    B.s[3]=yh;  B.s[4]=ylb;  B.s[5]=yh;
    B.s[6]=zh;  B.s[7]=zlb;  B.s[8]=zh;
    B.s[9]=xlb; B.s[10]=ylb; B.s[11]=zlb;
    B.s[12]=one; B.s[13]=one; B.s[14]=sih; B.s[15]=sil;
    float4* pad = (float4*)(pa + (size_t)i * 16);
    pad[0] = A.f[0]; pad[1] = A.f[1];
    float4* pbd = (float4*)(pb + (size_t)i * 16);
    pbd[0] = B.f[0]; pbd[1] = B.f[1];
}

// ---- 1b. split Wq/Wk/Wv into B-fragment layout: wsp[proj][outcol n][Wh k0..127 | Wl k0..127] ----
__global__ void __launch_bounds__(256) k_wsplit(const float* __restrict__ Wq, const float* __restrict__ Wk,
                                                const float* __restrict__ Wv, unsigned short* __restrict__ wsp) {
    const float* W = (blockIdx.x == 0) ? Wq : ((blockIdx.x == 1) ? Wk : Wv);
    unsigned short* dst = wsp + (size_t)blockIdx.x * HIDDEN * 256;
    for (int idx = threadIdx.x; idx < HIDDEN * HIDDEN; idx += 256) {
        int k = idx >> 7, n = idx & 127;
        float w = W[k * HIDDEN + n];
        unsigned short hi = f2bf(w);
        unsigned short lo = f2bf(w - bf2f(hi));
        dst[(size_t)n * 256 + k] = hi;
        dst[(size_t)n * 256 + 128 + k] = lo;
    }
}

// ---- 2. neighbor counts via 32x32x16 MFMA; boundary groups -> single flag, no rescan ----
__global__ void __launch_bounds__(256) k_neighbor(
        const unsigned short* __restrict__ pa, const unsigned short* __restrict__ pb,
        int* __restrict__ cnt, unsigned int* __restrict__ flg, unsigned int* __restrict__ nflag) {
    __shared__ unsigned short js[256 * 24];     // 48B row stride (16B-aligned halves)
    __shared__ unsigned int fbuf[LCAP];
    __shared__ unsigned int fcnt, fbase;
    int tid = threadIdx.x;
    if (tid == 0) fcnt = 0;
    int lane = tid & 63, w = tid >> 6;
    int half = lane >> 5, il = lane & 31;
    int i = blockIdx.x * 128 + w * 32 + il;
    bf16x8 bfrag = *(const bf16x8*)(pb + (size_t)i * 16 + half * 8);
    int jb0 = blockIdx.y * 1024;
    int acc = 0;
    for (int chv = 0; chv < 4; chv++) {
        int jb = jb0 + chv * 256;
        __syncthreads();
        {
            const float4* src = (const float4*)(pa + (size_t)(jb + tid) * 16);
            float4 v0 = src[0], v1 = src[1];
            float4* dst = (float4*)&js[tid * 24];
            dst[0] = v0; dst[1] = v1;
        }
        __syncthreads();
        #pragma unroll 2
        for (int t = 0; t < 8; t++) {
            bf16x8 afrag = *(const bf16x8*)&js[(t * 32 + il) * 24 + half * 8];
            f32x16 c = {0.f,0.f,0.f,0.f,0.f,0.f,0.f,0.f,0.f,0.f,0.f,0.f,0.f,0.f,0.f,0.f};
            c = __builtin_amdgcn_mfma_f32_32x32x16_bf16(afrag, bfrag, c, 0, 0, 0);
            int cs = 0, cl = 0;
            #pragma unroll
            for (int r = 0; r < 16; r++) {
                cs += (c[r] < 9.0f - TAU);
                cl += (c[r] < 9.0f + TAU);
            }
            if (cl == cs) {
                acc += cs;              // clean group: MFMA decision exact
            } else {                    // rare: defer whole 16-elem group to exact fixup
                unsigned jt9 = (unsigned)((jb >> 5) + t);
                unsigned xx = atomicAdd(&fcnt, 1u);
                if (xx < LCAP) fbuf[xx] = ((unsigned)i << 10) | (jt9 << 1) | (unsigned)half;
            }
        }
    }
    acc += __shfl_xor(acc, 32);
    if (half == 0) atomicAdd(&cnt[i], acc);
    __syncthreads();
    if (tid == 0) {
        unsigned cf = fcnt; if (cf > LCAP) cf = LCAP;
        fcnt = cf;
        fbase = atomicAdd(nflag, cf);
    }
    __syncthreads();
    unsigned cf = fcnt, fb = fbase;
    for (unsigned xx = tid; xx < cf; xx += 256) {
        unsigned di = fb + xx;
        if (di < FCAP) flg[di] = fbuf[xx];
    }
}

// ---- 2b. resolve flagged 16-element groups exactly (fp32) ----
__global__ void __launch_bounds__(256) k_fixup(const float* __restrict__ pos, const float* __restrict__ sq,
        const unsigned int* __restrict__ flg, const unsigned int* __restrict__ nflag,
        int* __restrict__ cnt) {
    int nf = (int)*nflag; if (nf > FCAP) nf = FCAP;
    for (int idx = blockIdx.x * 256 + threadIdx.x; idx < nf; idx += gridDim.x * 256) {
        unsigned pr = flg[idx];
        int i = (int)(pr >> 10);
        int jt = (int)((pr >> 1) & 511u) << 5;
        int half = (int)(pr & 1u);
        float xi = pos[i*3+0], yi = pos[i*3+1], zi = pos[i*3+2];
        float si = sq[i];
        int add = 0;
        #pragma unroll
        for (int r = 0; r < 16; r++) {
            int j = jt + (r & 3) + 8 * (r >> 2) + 4 * half;
            float xj = pos[j*3+0], yj = pos[j*3+1], zj = pos[j*3+2];
            float dot = fmaf(xi, xj, fmaf(yi, yj, zi * zj));
            float d2 = (si + sq[j]) - 2.0f * dot;
            add += (d2 < 9.0f);
        }
        atomicAdd(&cnt[i], add);
    }
}

// ---- 3. scores (fused) + exact top-KSEL radix select (parallel suffix scan) ----
__global__ void __launch_bounds__(1024) k_select(const float* __restrict__ dl, const int* __restrict__ cnt,
                                                 int* __restrict__ sel) {
    __shared__ unsigned int sk[NPTS];
    __shared__ int hist[256];
    __shared__ int scan2[256];
    __shared__ unsigned int s_prefix;
    __shared__ int s_rem, s_eqtot, s_nout, s_digit, s_cgt;
    int tid = threadIdx.x;
    for (int i = tid; i < NPTS; i += 1024) {
        float score = 1.0f / (1.0f + dl[i] / 5.0f) + 0.5f * (1.0f / (float)cnt[i]);
        unsigned int u = __float_as_uint(score);
        sk[i] = u ^ ((u & 0x80000000u) ? 0xFFFFFFFFu : 0x80000000u);
    }
    if (tid == 0) { s_prefix = 0; s_rem = KSEL; s_nout = 0; s_eqtot = 0; }
    __syncthreads();
    for (int p = 0; p < 4; p++) {
        int sh = 24 - 8 * p;
        if (tid < 256) hist[tid] = 0;
        __syncthreads();
        unsigned int pref = s_prefix;
        int shp = (p == 0) ? 0 : (32 - 8 * p);
        for (int i = tid; i < NPTS; i += 1024) {
            unsigned int key = sk[i];
            bool m = (p == 0) || ((key >> shp) == pref);
            if (m) atomicAdd(&hist[(key >> sh) & 255], 1);
        }
        __syncthreads();
        if (tid < 256) scan2[tid] = hist[tid];
        __syncthreads();
        for (int off = 1; off < 256; off <<= 1) {
            int v = 0;
            if (tid < 256) { v = scan2[tid]; if (tid + off < 256) v += scan2[tid + off]; }
            __syncthreads();
            if (tid < 256) scan2[tid] = v;
            __syncthreads();
        }
        int rem = s_rem;
        if (tid < 256) {
            int hi = scan2[tid];
            int lo = hi - hist[tid];
            if (hi >= rem && lo < rem) { s_digit = tid; s_cgt = lo; }
        }
        __syncthreads();
        if (tid == 0) {
            s_prefix = (s_prefix << 8) | (unsigned int)s_digit;
            s_rem = rem - s_cgt;
            if (p == 3) s_eqtot = hist[s_digit];
        }
        __syncthreads();
    }
    unsigned int T = s_prefix;
    int need_eq = s_rem;
    for (int i = tid; i < NPTS; i += 1024)
        if (sk[i] > T) sel[atomicAdd(&s_nout, 1)] = i;
    __syncthreads();
    if (s_eqtot == need_eq) {
        for (int i = tid; i < NPTS; i += 1024)
            if (sk[i] == T) sel[atomicAdd(&s_nout, 1)] = i;
    } else {
        for (int i = tid; i < NPTS; i += 1024) {
            if (sk[i] == T) {
                int rank = 0;
                for (int j = 0; j < i; j++) rank += (sk[j] == T);
                if (rank < need_eq) sel[atomicAdd(&s_nout, 1)] = i;
            }
        }
    }
}

// ---- 4. gather + node embed (fp32) + QKV projections via split-MFMA GEMM ----
// grid (128, 3): 32 q-rows/block, proj = blockIdx.y (0=Q,1=K,2=V)
// wave w: rows (w&1)*16, col half (w>>1); per tile: 8 K-chunks x 2 MFMA
__global__ void __launch_bounds__(256) k_qkv(const float* __restrict__ x, const int* __restrict__ sel,
        const float* __restrict__ Wn, const float* __restrict__ bn,
        const float* __restrict__ bq, const float* __restrict__ bk, const float* __restrict__ bv,
        const unsigned short* __restrict__ wsp,
        unsigned short* __restrict__ qpk, unsigned short* __restrict__ kpk,
        float* __restrict__ vg) {
    __shared__ float xs[32][8];
    __shared__ unsigned short hsp[32 * HROW];   // [row][Hh k0..127 | Hl k0..127], stride 264
    int tid = threadIdx.x;
    int r0 = blockIdx.x * 32;
    int proj = blockIdx.y;
    { int rr = tid >> 3, cc = tid & 7; xs[rr][cc] = x[(size_t)sel[r0 + rr] * 8 + cc]; }
    __syncthreads();
    {
        int d = tid & 127, rp = tid >> 7;
        float wn[8];
        #pragma unroll
        for (int c = 0; c < 8; c++) wn[c] = Wn[c * HIDDEN + d];
        float b = bn[d];
        for (int r = rp; r < 32; r += 2) {
            float a = b;
            #pragma unroll
            for (int c = 0; c < 8; c++) a = fmaf(xs[r][c], wn[c], a);
            unsigned short hi = f2bf(a);
            unsigned short lo = f2bf(a - bf2f(hi));
            hsp[r * HROW + d] = hi;
            hsp[r * HROW + 128 + d] = lo;
        }
    }
    __syncthreads();
    int lane = tid & 63, w = tid >> 6;
    int n = lane & 15, g = lane >> 4;
    int rloc = (w & 1) * 16;
    int chalf = w >> 1;
    const unsigned short* wb = wsp + (size_t)proj * HIDDEN * 256;
    const unsigned short* arow = &hsp[(rloc + n) * HROW + ((g < 2) ? 0 : 128) + (g & 1) * 8];
    int b1off = (g & 1) * 8;
    for (int tc = 0; tc < 4; tc++) {
        int col0 = chalf * 64 + tc * 16;
        const unsigned short* bcol = wb + (size_t)(col0 + n) * 256;
        f32x4 acc = {0.f, 0.f, 0.f, 0.f};
        #pragma unroll
        for (int c = 0; c < 8; c++) {
            bf16x8 af = *(const bf16x8*)(arow + c * 16);
            bf16x8 b1 = *(const bf16x8*)(bcol + c * 16 + b1off);          // [Wh|Wh]
            bf16x8 b2 = {0,0,0,0,0,0,0,0};                                 // [Wl|0]
            if (g < 2) b2 = *(const bf16x8*)(bcol + 128 + c * 16 + b1off);
            acc = __builtin_amdgcn_mfma_f32_16x16x32_bf16(af, b1, acc, 0, 0, 0);
            acc = __builtin_amdgcn_mfma_f32_16x16x32_bf16(af, b2, acc, 0, 0, 0);
        }
        int col = col0 + n;
        int hh = col >> 4, dd = col & 15;
        if (proj == 0) {
            float bb = bq[col];
            #pragma unroll
            for (int r = 0; r < 4; r++) {
                int qrow = r0 + rloc + g * 4 + r;
                float val = (acc[r] + bb) * 0.36067376022224085f;   // log2(e)/4
                unsigned short hi = f2bf(val);
                unsigned short lo = f2bf(val - bf2f(hi));
                size_t idx = ((size_t)(hh * KSEL) + qrow) * 32 + dd;
                qpk[idx] = hi; qpk[idx + 16] = lo;
            }
        } else if (proj == 1) {
            float bb = bk[col];
            #pragma unroll
            for (int r = 0; r < 4; r++) {
                int qrow = r0 + rloc + g * 4 + r;
                float val = acc[r] + bb;
                unsigned short hi = f2bf(val);
                unsigned short lo = f2bf(val - bf2f(hi));
                size_t idx = ((size_t)(hh * KSEL) + qrow) * 32 + dd;
                kpk[idx] = hi; kpk[idx + 16] = lo;
            }
        } else {
            float bb = bv[col];
            #pragma unroll
            for (int r = 0; r < 4; r++) {
                int qrow = r0 + rloc + g * 4 + r;
                vg[(size_t)qrow * HIDDEN + col] = acc[r] + bb;
            }
        }
    }
}

// ---- 5. phase 1: row sums l_q via MFMA; chunked LDS (256 rows, 80B stride) ----
__global__ void __launch_bounds__(256) k_attn_l(
        const unsigned short* __restrict__ qpk, const unsigned short* __restrict__ kpk,
        float* __restrict__ lp) {
    __shared__ unsigned short smem[256 * 40];
    int tid = threadIdx.x;
    int ks = blockIdx.x, yg = blockIdx.y, h = blockIdx.z;
    size_t hb = (size_t)h * KSEL;
    int lane = tid & 63, w = tid >> 6;
    int n = lane & 15, g = lane >> 4;
    int q0w = yg * 64 + w * 16;
    bf16x8 afrag = *(const bf16x8*)(qpk + (hb + q0w + n) * 32 + g * 8); // A=[Qh|Ql]
    float l0 = 0.f, l1 = 0.f, l2 = 0.f, l3 = 0.f;
    int b1off = (g & 1) * 8;
    int b2off = 16 + g * 8;
    for (int kc = 0; kc < 4; kc++) {
        __syncthreads();
        {
            int krow = ks * 1024 + kc * 256 + tid;
            const float4* src = (const float4*)(kpk + (hb + krow) * 32);
            float4 a0 = src[0], a1 = src[1], a2 = src[2], a3 = src[3];
            float4* dst = (float4*)&smem[tid * 40];
            dst[0] = a0; dst[1] = a1; dst[2] = a2; dst[3] = a3;
        }
        __syncthreads();
        #pragma unroll 4
        for (int t = 0; t < 16; t++) {
            const unsigned short* rowp = &smem[(t * 16 + n) * 40];
            bf16x8 b1 = *(const bf16x8*)(rowp + b1off);            // [Kh|Kh]
            bf16x8 b2 = {0,0,0,0,0,0,0,0};                          // [Kl|0]
            if (g < 2) b2 = *(const bf16x8*)(rowp + b2off);
            f32x4 c = {0.f, 0.f, 0.f, 0.f};
            c = __builtin_amdgcn_mfma_f32_16x16x32_bf16(afrag, b1, c, 0, 0, 0);
            c = __builtin_amdgcn_mfma_f32_16x16x32_bf16(afrag, b2, c, 0, 0, 0);
            l0 += E2(c[0]); l1 += E2(c[1]); l2 += E2(c[2]); l3 += E2(c[3]);
        }
    }
    #pragma unroll
    for (int m = 1; m < 16; m <<= 1) {
        l0 += __shfl_xor(l0, m); l1 += __shfl_xor(l1, m);
        l2 += __shfl_xor(l2, m); l3 += __shfl_xor(l3, m);
    }
    if (n == 0) {
        size_t base = (hb + q0w + g * 4) * NSLICE + ks;
        lp[base]            = l0; lp[base + NSLICE]     = l1;
        lp[base + 2*NSLICE] = l2; lp[base + 3*NSLICE]   = l3;
    }
}

// ---- 6. phase 2: column weights w_j = sum_q exp(s)/l_q (A = K-row [Kh|Kl]; 1/l inline) ----
__global__ void __launch_bounds__(256) k_attn_w(
        const unsigned short* __restrict__ qpk, const unsigned short* __restrict__ kpk,
        const float* __restrict__ lp, float* __restrict__ wp) {
    __shared__ unsigned short smem[256 * 40];
    __shared__ float rls[256];
    int tid = threadIdx.x;
    int qs = blockIdx.x, yg = blockIdx.y, h = blockIdx.z;
    size_t hb = (size_t)h * KSEL;
    int lane = tid & 63, w = tid >> 6;
    int n = lane & 15, g = lane >> 4;
    int j0w = yg * 64 + w * 16;
    bf16x8 afrag = *(const bf16x8*)(kpk + (hb + j0w + n) * 32 + g * 8); // A=[Kh|Kl]
    float w0 = 0.f, w1 = 0.f, w2 = 0.f, w3 = 0.f;
    int b1off = (g & 1) * 8;
    int b2off = 16 + g * 8;
    for (int qc = 0; qc < 4; qc++) {
        __syncthreads();
        {
            int qrow = qs * 1024 + qc * 256 + tid;
            const float4* src = (const float4*)(qpk + (hb + qrow) * 32);
            float4 a0 = src[0], a1 = src[1], a2 = src[2], a3 = src[3];
            float4* dst = (float4*)&smem[tid * 40];
            dst[0] = a0; dst[1] = a1; dst[2] = a2; dst[3] = a3;
            float4 p = ((const float4*)lp)[hb + qrow];
            rls[tid] = 1.0f / ((p.x + p.y) + (p.z + p.w));
        }
        __syncthreads();
        #pragma unroll 4
        for (int t = 0; t < 16; t++) {
            const unsigned short* rowp = &smem[(t * 16 + n) * 40];
            bf16x8 b1 = *(const bf16x8*)(rowp + b1off);            // [Qh|Qh]
            bf16x8 b2 = {0,0,0,0,0,0,0,0};                          // [Ql|0]
            if (g < 2) b2 = *(const bf16x8*)(rowp + b2off);
            f32x4 c = {0.f, 0.f, 0.f, 0.f};
            c = __builtin_amdgcn_mfma_f32_16x16x32_bf16(afrag, b1, c, 0, 0, 0);
            c = __builtin_amdgcn_mfma_f32_16x16x32_bf16(afrag, b2, c, 0, 0, 0);
            float rv = rls[t * 16 + n];
            w0 = fmaf(E2(c[0]), rv, w0); w1 = fmaf(E2(c[1]), rv, w1);
            w2 = fmaf(E2(c[2]), rv, w2); w3 = fmaf(E2(c[3]), rv, w3);
        }
    }
    #pragma unroll
    for (int m = 1; m < 16; m <<= 1) {
        w0 += __shfl_xor(w0, m); w1 += __shfl_xor(w1, m);
        w2 += __shfl_xor(w2, m); w3 += __shfl_xor(w3, m);
    }
    if (n == 0) {
        size_t base = (hb + j0w + g * 4) * NSLICE + qs;
        wp[base]            = w0; wp[base + NSLICE]     = w1;
        wp[base + 2*NSLICE] = w2; wp[base + 3*NSLICE]   = w3;
    }
}

// ---- 7. pooled_av[d] += (1/K) sum_j w[h(d)][j] * v[j][d]  (32 j per block) ----
__global__ void __launch_bounds__(256) k_colsum(const float* __restrict__ wp, const float* __restrict__ vg,
                                                float* __restrict__ pav) {
    __shared__ float wl[NHEADS][32];
    __shared__ float red[128];
    int tid = threadIdx.x;
    int j0 = blockIdx.x * 32;
    {
        int h = tid >> 5, jl = tid & 31;
        float4 p = ((const float4*)wp)[(size_t)h * KSEL + j0 + jl];
        wl[h][jl] = (p.x + p.y) + (p.z + p.w);
    }
    __syncthreads();
    int d = tid & 127, g = tid >> 7;
    int h = d >> 4;
    float acc = 0.f;
    for (int jl = g * 16; jl < g * 16 + 16; jl++)
        acc = fmaf(wl[h][jl], vg[(size_t)(j0 + jl) * HIDDEN + d], acc);
    if (g == 1) red[d] = acc;
    __syncthreads();
    if (g == 0) atomicAdd(&pav[d], (acc + red[d]) * (1.0f / (float)KSEL));
}

// ---- 8. out-proj + pool MLP ----
__global__ void __launch_bounds__(256) k_final(const float* __restrict__ pav,
        const float* __restrict__ Wo, const float* __restrict__ bo,
        const float* __restrict__ W1, const float* __restrict__ b1,
        const float* __restrict__ W2, const float* __restrict__ b2,
        float* __restrict__ out) {
    __shared__ float sp[HIDDEN];
    __shared__ float st[OUTD];
    int t = threadIdx.x;
    if (t < HIDDEN) {
        float a = bo[t];
        for (int c = 0; c < HIDDEN; c++) a = fmaf(pav[c], Wo[c * HIDDEN + t], a);
        sp[t] = a;
    }
    __syncthreads();
    {
        float a = b1[t];
        for (int c = 0; c < HIDDEN; c++) a = fmaf(sp[c], W1[c * OUTD + t], a);
        st[t] = fmaxf(a, 0.f);
    }
    __syncthreads();
    {
        float o = b2[t];
        for (int c = 0; c < OUTD; c++) o = fmaf(st[c], W2[c * OUTD + t], o);
        out[t] = o;
    }
}

extern "C" void kernel_launch(void* const* d_in, const int* in_sizes, int n_in,
                              void* d_out, int out_size, void* d_ws, size_t ws_size,
                              hipStream_t stream) {
    (void)n_in; (void)out_size; (void)ws_size;
    const float* x   = (const float*)d_in[0];
    const float* pos = (const float*)d_in[1];
    const float* lig = (const float*)d_in[2];
    const float* Wn  = (const float*)d_in[3];
    const float* bn  = (const float*)d_in[4];
    const float* Wq  = (const float*)d_in[5];
    const float* bq  = (const float*)d_in[6];
    const float* Wk  = (const float*)d_in[7];
    const float* bk  = (const float*)d_in[8];
    const float* Wv  = (const float*)d_in[9];
    const float* bv  = (const float*)d_in[10];
    const float* Wo  = (const float*)d_in[11];
    const float* bo  = (const float*)d_in[12];
    const float* W1  = (const float*)d_in[13];
    const float* b1  = (const float*)d_in[14];
    const float* W2  = (const float*)d_in[15];
    const float* b2  = (const float*)d_in[16];
    int M = in_sizes[2] / 3;

    char* ws = (char*)d_ws;
    unsigned short* pa  = (unsigned short*)(ws + OFF_PA);
    unsigned short* pb  = (unsigned short*)(ws + OFF_PB);
    float*          sq  = (float*)(ws + OFF_SQ);
    float*          dl  = (float*)(ws + OFF_DL);
    int*            cnt = (int*)  (ws + OFF_CNT);
    unsigned int*   nfl = (unsigned int*)(ws + OFF_NFLAG);
    unsigned int*   flg = (unsigned int*)(ws + OFF_FLG);
    int*            sel = (int*)  (ws + OFF_SEL);
    unsigned short* qpk = (unsigned short*)(ws + OFF_QPK);
    unsigned short* kpk = (unsigned short*)(ws + OFF_KPK);
    float*          vg  = (float*)(ws + OFF_V);
    float*          lp  = (float*)(ws + OFF_LP);
    float*          wp  = (float*)(ws + OFF_WP);
    float*          pav = (float*)(ws + OFF_PAV);
    unsigned short* wsp = (unsigned short*)(ws + OFF_WSP);

    hipLaunchKernelGGL(k_prep,     dim3(64),       dim3(256),  0, stream, pos, lig, M, pa, pb, sq, dl, cnt, nfl, pav);
    hipLaunchKernelGGL(k_wsplit,   dim3(3),        dim3(256),  0, stream, Wq, Wk, Wv, wsp);
    hipLaunchKernelGGL(k_neighbor, dim3(128, 16),  dim3(256),  0, stream, pa, pb, cnt, flg, nfl);
    hipLaunchKernelGGL(k_fixup,    dim3(128),      dim3(256),  0, stream, pos, sq, flg, nfl, cnt);
    hipLaunchKernelGGL(k_select,   dim3(1),        dim3(1024), 0, stream, dl, cnt, sel);
    hipLaunchKernelGGL(k_qkv,      dim3(128, 3),   dim3(256),  0, stream, x, sel, Wn, bn, bq, bk, bv, wsp, qpk, kpk, vg);
    hipLaunchKernelGGL(k_attn_l,   dim3(4, 64, 8), dim3(256),  0, stream, qpk, kpk, lp);
    hipLaunchKernelGGL(k_attn_w,   dim3(4, 64, 8), dim3(256),  0, stream, qpk, kpk, lp, wp);
    hipLaunchKernelGGL(k_colsum,   dim3(KSEL/32),  dim3(256),  0, stream, wp, vg, pav);
    hipLaunchKernelGGL(k_final,    dim3(1),        dim3(256),  0, stream, pav, Wo, bo, W1, b1, W2, b2, (float*)d_out);
}

// Round 13
// 276.069 us; speedup vs baseline: 1.0438x; 1.0438x over previous
//
#include <hip/hip_runtime.h>
#include <cstdint>
#include <cstddef>

#define NPTS 16384
#define KSEL 4096
#define HIDDEN 128
#define NHEADS 8
#define DHEAD 16
#define OUTD 256
#define NSLICE 4   // k/q slices for attn partials
#define FCAP 262144
#define LCAP 2048
#define TAU 0.15f
#define HROW 264   // LDS row stride (shorts) for packed h: non-pow2, 16B-multiple

typedef __attribute__((ext_vector_type(8))) short bf16x8;
typedef __attribute__((ext_vector_type(4))) float f32x4;
typedef __attribute__((ext_vector_type(16))) float f32x16;

#if defined(__has_builtin)
#if __has_builtin(__builtin_amdgcn_exp2f)
#define E2(x) __builtin_amdgcn_exp2f(x)
#endif
#endif
#ifndef E2
#define E2(x) exp2f(x)
#endif

// ---- workspace layout (bytes) ----
constexpr size_t OFF_PA    = 1024;                         // NPTS*16 bf16 (A-side packed)
constexpr size_t OFF_PB    = OFF_PA  + (size_t)NPTS*32;    // NPTS*16 bf16 (B-side packed)
constexpr size_t OFF_SQ    = OFF_PB  + (size_t)NPTS*32;
constexpr size_t OFF_DL    = OFF_SQ  + (size_t)NPTS*4;
constexpr size_t OFF_CNT   = OFF_DL  + (size_t)NPTS*4;     // int (zeroed by k_prep)
constexpr size_t OFF_NFLAG = OFF_CNT + (size_t)NPTS*4;     // uint (zeroed by k_prep)
constexpr size_t OFF_FLG   = OFF_NFLAG + 1024;             // FCAP uints (group flags)
constexpr size_t OFF_SEL   = OFF_FLG + (size_t)FCAP*4;     // KSEL int
constexpr size_t SZ_PK     = (size_t)NHEADS*KSEL*32*2;     // 2 MB packed [hi16|lo16] bf16
constexpr size_t OFF_QPK   = OFF_SEL + (size_t)KSEL*4;
constexpr size_t OFF_KPK   = OFF_QPK + SZ_PK;
constexpr size_t OFF_V     = OFF_KPK + SZ_PK;                      // KSEL*128 f32
constexpr size_t OFF_LP    = OFF_V  + (size_t)KSEL*HIDDEN*4;       // 8*4096*4 f32 partial l
constexpr size_t OFF_WP    = OFF_LP + (size_t)NHEADS*KSEL*NSLICE*4; // 8*4096*4 f32 partial w
constexpr size_t OFF_PAV   = OFF_WP + (size_t)NHEADS*KSEL*NSLICE*4; // 128 f32
constexpr size_t OFF_WSP   = OFF_PAV + 1024;               // 3*128*256 shorts (split W, B-frag layout)

__device__ __forceinline__ unsigned short f2bf(float f) {
    union { float f; unsigned u; } v; v.f = f;
    unsigned r = v.u + 0x7fffu + ((v.u >> 16) & 1u);
    return (unsigned short)(r >> 16);
}
__device__ __forceinline__ float bf2f(unsigned short h) {
    union { unsigned u; float f; } v; v.u = ((unsigned)h) << 16;
    return v.f;
}

// ---- 1. prep (blocks 0-63): center, sq, d_lig, packed coords; zero cnt/nflag/pav.
//         blocks 64-66: split Wq/Wk/Wv into B-frag layout wsp[proj][col][Wh k0..127 | Wl k0..127]
__global__ void __launch_bounds__(256) k_prep(const float* __restrict__ pos, const float* __restrict__ lig, int M,
                       unsigned short* __restrict__ pa, unsigned short* __restrict__ pb,
                       float* __restrict__ sq, float* __restrict__ dl,
                       int* __restrict__ cnt, unsigned int* __restrict__ nflag, float* __restrict__ pav,
                       const float* __restrict__ Wq, const float* __restrict__ Wk, const float* __restrict__ Wv,
                       unsigned short* __restrict__ wsp) {
    __shared__ float ls[128];
    __shared__ float ctr[3];
    int tid = threadIdx.x;
    if (blockIdx.x >= 64) {     // ---- wsplit part ----
        int proj = blockIdx.x - 64;
        const float* W = (proj == 0) ? Wq : ((proj == 1) ? Wk : Wv);
        unsigned short* dst = wsp + (size_t)proj * HIDDEN * 256;
        for (int idx = tid; idx < HIDDEN * HIDDEN; idx += 256) {
            int k = idx >> 7, n = idx & 127;
            float w = W[k * HIDDEN + n];
            unsigned short hi = f2bf(w);
            unsigned short lo = f2bf(w - bf2f(hi));
            dst[(size_t)n * 256 + k] = hi;
            dst[(size_t)n * 256 + 128 + k] = lo;
        }
        return;
    }
    int i = blockIdx.x * 256 + tid;
    cnt[i] = 0;
    if (i == 0) *nflag = 0;
    if (blockIdx.x == 0 && tid < HIDDEN) pav[tid] = 0.f;
    for (int k = tid; k < 3 * M; k += 256) ls[k] = lig[k];
    __syncthreads();
    if (tid < 3) {
        float s = 0.f;
        for (int k = 0; k < M; k++) s += ls[k * 3 + tid];
        ctr[tid] = s / (float)M;
    }
    __syncthreads();
    float x = pos[i*3+0], y = pos[i*3+1], z = pos[i*3+2];
    float s = (x*x + y*y) + z*z;
    sq[i] = s;
    float dx = x - ctr[0], dy = y - ctr[1], dz = z - ctr[2];
    dl[i] = sqrtf((dx*dx + dy*dy) + dz*dz);
    unsigned short xh = f2bf(x); float xr = bf2f(xh); float xl = x - xr;
    unsigned short yh = f2bf(y); float yr = bf2f(yh); float yl = y - yr;
    unsigned short zh = f2bf(z); float zr = bf2f(zh); float zl = z - zr;
    unsigned short xlb = f2bf(xl), ylb = f2bf(yl), zlb = f2bf(zl);
    unsigned short xhA = f2bf(-2.f*xr), xlA = f2bf(-2.f*xl);
    unsigned short yhA = f2bf(-2.f*yr), ylA = f2bf(-2.f*yl);
    unsigned short zhA = f2bf(-2.f*zr), zlA = f2bf(-2.f*zl);
    unsigned short sih = f2bf(s);
    unsigned short sil = f2bf(s - bf2f(sih));
    unsigned short one = f2bf(1.0f);
    union { unsigned short s[16]; float4 f[2]; } A, B;
    A.s[0]=xhA; A.s[1]=xhA; A.s[2]=xlA;
    A.s[3]=yhA; A.s[4]=yhA; A.s[5]=ylA;
    A.s[6]=zhA; A.s[7]=zhA; A.s[8]=zlA;
    A.s[9]=xlA; A.s[10]=ylA; A.s[11]=zlA;
    A.s[12]=sih; A.s[13]=sil; A.s[14]=one; A.s[15]=one;
    B.s[0]=xh;  B.s[1]=xlb;  B.s[2]=xh;
    B.s[3]=yh;  B.s[4]=ylb;  B.s[5]=yh;
    B.s[6]=zh;  B.s[7]=zlb;  B.s[8]=zh;
    B.s[9]=xlb; B.s[10]=ylb; B.s[11]=zlb;
    B.s[12]=one; B.s[13]=one; B.s[14]=sih; B.s[15]=sil;
    float4* pad = (float4*)(pa + (size_t)i * 16);
    pad[0] = A.f[0]; pad[1] = A.f[1];
    float4* pbd = (float4*)(pb + (size_t)i * 16);
    pbd[0] = B.f[0]; pbd[1] = B.f[1];
}

// ---- 2. neighbor counts via 32x32x16 MFMA; boundary groups -> single flag, no rescan ----
__global__ void __launch_bounds__(256) k_neighbor(
        const unsigned short* __restrict__ pa, const unsigned short* __restrict__ pb,
        int* __restrict__ cnt, unsigned int* __restrict__ flg, unsigned int* __restrict__ nflag) {
    __shared__ unsigned short js[256 * 24];     // 48B row stride (16B-aligned halves)
    __shared__ unsigned int fbuf[LCAP];
    __shared__ unsigned int fcnt, fbase;
    int tid = threadIdx.x;
    if (tid == 0) fcnt = 0;
    int lane = tid & 63, w = tid >> 6;
    int half = lane >> 5, il = lane & 31;
    int i = blockIdx.x * 128 + w * 32 + il;
    bf16x8 bfrag = *(const bf16x8*)(pb + (size_t)i * 16 + half * 8);
    int jb0 = blockIdx.y * 1024;
    int acc = 0;
    for (int chv = 0; chv < 4; chv++) {
        int jb = jb0 + chv * 256;
        __syncthreads();
        {
            const float4* src = (const float4*)(pa + (size_t)(jb + tid) * 16);
            float4 v0 = src[0], v1 = src[1];
            float4* dst = (float4*)&js[tid * 24];
            dst[0] = v0; dst[1] = v1;
        }
        __syncthreads();
        #pragma unroll 2
        for (int t = 0; t < 8; t++) {
            bf16x8 afrag = *(const bf16x8*)&js[(t * 32 + il) * 24 + half * 8];
            f32x16 c = {0.f,0.f,0.f,0.f,0.f,0.f,0.f,0.f,0.f,0.f,0.f,0.f,0.f,0.f,0.f,0.f};
            c = __builtin_amdgcn_mfma_f32_32x32x16_bf16(afrag, bfrag, c, 0, 0, 0);
            int cs = 0, cl = 0;
            #pragma unroll
            for (int r = 0; r < 16; r++) {
                cs += (c[r] < 9.0f - TAU);
                cl += (c[r] < 9.0f + TAU);
            }
            if (cl == cs) {
                acc += cs;              // clean group: MFMA decision exact
            } else {                    // rare: defer whole 16-elem group to exact fixup
                unsigned jt9 = (unsigned)((jb >> 5) + t);
                unsigned xx = atomicAdd(&fcnt, 1u);
                if (xx < LCAP) fbuf[xx] = ((unsigned)i << 10) | (jt9 << 1) | (unsigned)half;
            }
        }
    }
    acc += __shfl_xor(acc, 32);
    if (half == 0) atomicAdd(&cnt[i], acc);
    __syncthreads();
    if (tid == 0) {
        unsigned cf = fcnt; if (cf > LCAP) cf = LCAP;
        fcnt = cf;
        fbase = atomicAdd(nflag, cf);
    }
    __syncthreads();
    unsigned cf = fcnt, fb = fbase;
    for (unsigned xx = tid; xx < cf; xx += 256) {
        unsigned di = fb + xx;
        if (di < FCAP) flg[di] = fbuf[xx];
    }
}

// ---- 2b. resolve flagged 16-element groups exactly (fp32) ----
__global__ void __launch_bounds__(256) k_fixup(const float* __restrict__ pos, const float* __restrict__ sq,
        const unsigned int* __restrict__ flg, const unsigned int* __restrict__ nflag,
        int* __restrict__ cnt) {
    int nf = (int)*nflag; if (nf > FCAP) nf = FCAP;
    for (int idx = blockIdx.x * 256 + threadIdx.x; idx < nf; idx += gridDim.x * 256) {
        unsigned pr = flg[idx];
        int i = (int)(pr >> 10);
        int jt = (int)((pr >> 1) & 511u) << 5;
        int half = (int)(pr & 1u);
        float xi = pos[i*3+0], yi = pos[i*3+1], zi = pos[i*3+2];
        float si = sq[i];
        int add = 0;
        #pragma unroll
        for (int r = 0; r < 16; r++) {
            int j = jt + (r & 3) + 8 * (r >> 2) + 4 * half;
            float xj = pos[j*3+0], yj = pos[j*3+1], zj = pos[j*3+2];
            float dot = fmaf(xi, xj, fmaf(yi, yj, zi * zj));
            float d2 = (si + sq[j]) - 2.0f * dot;
            add += (d2 < 9.0f);
        }
        atomicAdd(&cnt[i], add);
    }
}

// ---- 3. scores (fused) + exact top-KSEL radix select (parallel suffix scan) ----
__global__ void __launch_bounds__(1024) k_select(const float* __restrict__ dl, const int* __restrict__ cnt,
                                                 int* __restrict__ sel) {
    __shared__ unsigned int sk[NPTS];
    __shared__ int hist[256];
    __shared__ int scan2[256];
    __shared__ unsigned int s_prefix;
    __shared__ int s_rem, s_eqtot, s_nout, s_digit, s_cgt;
    int tid = threadIdx.x;
    for (int i = tid; i < NPTS; i += 1024) {
        float score = 1.0f / (1.0f + dl[i] / 5.0f) + 0.5f * (1.0f / (float)cnt[i]);
        unsigned int u = __float_as_uint(score);
        sk[i] = u ^ ((u & 0x80000000u) ? 0xFFFFFFFFu : 0x80000000u);
    }
    if (tid == 0) { s_prefix = 0; s_rem = KSEL; s_nout = 0; s_eqtot = 0; }
    __syncthreads();
    for (int p = 0; p < 4; p++) {
        int sh = 24 - 8 * p;
        if (tid < 256) hist[tid] = 0;
        __syncthreads();
        unsigned int pref = s_prefix;
        int shp = (p == 0) ? 0 : (32 - 8 * p);
        for (int i = tid; i < NPTS; i += 1024) {
            unsigned int key = sk[i];
            bool m = (p == 0) || ((key >> shp) == pref);
            if (m) atomicAdd(&hist[(key >> sh) & 255], 1);
        }
        __syncthreads();
        if (tid < 256) scan2[tid] = hist[tid];
        __syncthreads();
        for (int off = 1; off < 256; off <<= 1) {
            int v = 0;
            if (tid < 256) { v = scan2[tid]; if (tid + off < 256) v += scan2[tid + off]; }
            __syncthreads();
            if (tid < 256) scan2[tid] = v;
            __syncthreads();
        }
        int rem = s_rem;
        if (tid < 256) {
            int hi = scan2[tid];
            int lo = hi - hist[tid];
            if (hi >= rem && lo < rem) { s_digit = tid; s_cgt = lo; }
        }
        __syncthreads();
        if (tid == 0) {
            s_prefix = (s_prefix << 8) | (unsigned int)s_digit;
            s_rem = rem - s_cgt;
            if (p == 3) s_eqtot = hist[s_digit];
        }
        __syncthreads();
    }
    unsigned int T = s_prefix;
    int need_eq = s_rem;
    for (int i = tid; i < NPTS; i += 1024)
        if (sk[i] > T) sel[atomicAdd(&s_nout, 1)] = i;
    __syncthreads();
    if (s_eqtot == need_eq) {
        for (int i = tid; i < NPTS; i += 1024)
            if (sk[i] == T) sel[atomicAdd(&s_nout, 1)] = i;
    } else {
        for (int i = tid; i < NPTS; i += 1024) {
            if (sk[i] == T) {
                int rank = 0;
                for (int j = 0; j < i; j++) rank += (sk[j] == T);
                if (rank < need_eq) sel[atomicAdd(&s_nout, 1)] = i;
            }
        }
    }
}

// ---- 4. gather + node embed (fp32) + QKV projections via split-MFMA GEMM ----
// grid (128, 3): 32 q-rows/block, proj = blockIdx.y (0=Q,1=K,2=V)
__global__ void __launch_bounds__(256) k_qkv(const float* __restrict__ x, const int* __restrict__ sel,
        const float* __restrict__ Wn, const float* __restrict__ bn,
        const float* __restrict__ bq, const float* __restrict__ bk, const float* __restrict__ bv,
        const unsigned short* __restrict__ wsp,
        unsigned short* __restrict__ qpk, unsigned short* __restrict__ kpk,
        float* __restrict__ vg) {
    __shared__ float xs[32][8];
    __shared__ unsigned short hsp[32 * HROW];   // [row][Hh k0..127 | Hl k0..127], stride 264
    int tid = threadIdx.x;
    int r0 = blockIdx.x * 32;
    int proj = blockIdx.y;
    { int rr = tid >> 3, cc = tid & 7; xs[rr][cc] = x[(size_t)sel[r0 + rr] * 8 + cc]; }
    __syncthreads();
    {
        int d = tid & 127, rp = tid >> 7;
        float wn[8];
        #pragma unroll
        for (int c = 0; c < 8; c++) wn[c] = Wn[c * HIDDEN + d];
        float b = bn[d];
        for (int r = rp; r < 32; r += 2) {
            float a = b;
            #pragma unroll
            for (int c = 0; c < 8; c++) a = fmaf(xs[r][c], wn[c], a);
            unsigned short hi = f2bf(a);
            unsigned short lo = f2bf(a - bf2f(hi));
            hsp[r * HROW + d] = hi;
            hsp[r * HROW + 128 + d] = lo;
        }
    }
    __syncthreads();
    int lane = tid & 63, w = tid >> 6;
    int n = lane & 15, g = lane >> 4;
    int rloc = (w & 1) * 16;
    int chalf = w >> 1;
    const unsigned short* wb = wsp + (size_t)proj * HIDDEN * 256;
    const unsigned short* arow = &hsp[(rloc + n) * HROW + ((g < 2) ? 0 : 128) + (g & 1) * 8];
    int b1off = (g & 1) * 8;
    for (int tc = 0; tc < 4; tc++) {
        int col0 = chalf * 64 + tc * 16;
        const unsigned short* bcol = wb + (size_t)(col0 + n) * 256;
        f32x4 acc = {0.f, 0.f, 0.f, 0.f};
        #pragma unroll
        for (int c = 0; c < 8; c++) {
            bf16x8 af = *(const bf16x8*)(arow + c * 16);
            bf16x8 b1 = *(const bf16x8*)(bcol + c * 16 + b1off);          // [Wh|Wh]
            bf16x8 b2 = {0,0,0,0,0,0,0,0};                                 // [Wl|0]
            if (g < 2) b2 = *(const bf16x8*)(bcol + 128 + c * 16 + b1off);
            acc = __builtin_amdgcn_mfma_f32_16x16x32_bf16(af, b1, acc, 0, 0, 0);
            acc = __builtin_amdgcn_mfma_f32_16x16x32_bf16(af, b2, acc, 0, 0, 0);
        }
        int col = col0 + n;
        int hh = col >> 4, dd = col & 15;
        if (proj == 0) {
            float bb = bq[col];
            #pragma unroll
            for (int r = 0; r < 4; r++) {
                int qrow = r0 + rloc + g * 4 + r;
                float val = (acc[r] + bb) * 0.36067376022224085f;   // log2(e)/4
                unsigned short hi = f2bf(val);
                unsigned short lo = f2bf(val - bf2f(hi));
                size_t idx = ((size_t)(hh * KSEL) + qrow) * 32 + dd;
                qpk[idx] = hi; qpk[idx + 16] = lo;
            }
        } else if (proj == 1) {
            float bb = bk[col];
            #pragma unroll
            for (int r = 0; r < 4; r++) {
                int qrow = r0 + rloc + g * 4 + r;
                float val = acc[r] + bb;
                unsigned short hi = f2bf(val);
                unsigned short lo = f2bf(val - bf2f(hi));
                size_t idx = ((size_t)(hh * KSEL) + qrow) * 32 + dd;
                kpk[idx] = hi; kpk[idx + 16] = lo;
            }
        } else {
            float bb = bv[col];
            #pragma unroll
            for (int r = 0; r < 4; r++) {
                int qrow = r0 + rloc + g * 4 + r;
                vg[(size_t)qrow * HIDDEN + col] = acc[r] + bb;
            }
        }
    }
}

// ---- 5. phase 1: row sums l_q via 32x32x16 MFMA (3 per 1024 scores) ----
// grid (NSLICE=4 ks, 32 yg, 8 h); block 256 = 4 waves; wave = 32 q x 1024-j strip
__global__ void __launch_bounds__(256) k_attn_l(
        const unsigned short* __restrict__ qpk, const unsigned short* __restrict__ kpk,
        float* __restrict__ lp) {
    __shared__ unsigned short smem[256 * 40];   // staged K rows [Kh16|Kl16], stride 40 shorts
    int tid = threadIdx.x;
    int ks = blockIdx.x, yg = blockIdx.y, h = blockIdx.z;
    size_t hb = (size_t)h * KSEL;
    int lane = tid & 63, w = tid >> 6;
    int n = lane & 31, half = lane >> 5;
    int q0 = yg * 128 + w * 32;
    const unsigned short* qrow = qpk + (hb + q0 + n) * 32;
    bf16x8 aQh = *(const bf16x8*)(qrow + half * 8);        // A[m=n][k=8*half+reg]
    bf16x8 aQl = *(const bf16x8*)(qrow + 16 + half * 8);
    float lacc[16];
    #pragma unroll
    for (int r = 0; r < 16; r++) lacc[r] = 0.f;
    for (int kc = 0; kc < 4; kc++) {
        __syncthreads();
        {
            int krow = ks * 1024 + kc * 256 + tid;
            const float4* src = (const float4*)(kpk + (hb + krow) * 32);
            float4 a0 = src[0], a1 = src[1], a2 = src[2], a3 = src[3];
            float4* dst = (float4*)&smem[tid * 40];
            dst[0] = a0; dst[1] = a1; dst[2] = a2; dst[3] = a3;
        }
        __syncthreads();
        #pragma unroll 2
        for (int t = 0; t < 8; t++) {
            const unsigned short* rowp = &smem[(t * 32 + n) * 40];
            bf16x8 bKh = *(const bf16x8*)(rowp + half * 8);     // B[k][n=j-local]
            bf16x8 bKl = *(const bf16x8*)(rowp + 16 + half * 8);
            f32x16 c = {0.f,0.f,0.f,0.f,0.f,0.f,0.f,0.f,0.f,0.f,0.f,0.f,0.f,0.f,0.f,0.f};
            c = __builtin_amdgcn_mfma_f32_32x32x16_bf16(aQh, bKh, c, 0, 0, 0);
            c = __builtin_amdgcn_mfma_f32_32x32x16_bf16(aQl, bKh, c, 0, 0, 0);
            c = __builtin_amdgcn_mfma_f32_32x32x16_bf16(aQh, bKl, c, 0, 0, 0);
            #pragma unroll
            for (int r = 0; r < 16; r++) lacc[r] += E2(c[r]);
        }
    }
    #pragma unroll
    for (int m = 1; m < 32; m <<= 1) {
        #pragma unroll
        for (int r = 0; r < 16; r++) lacc[r] += __shfl_xor(lacc[r], m);
    }
    if (n == 0) {
        #pragma unroll
        for (int r = 0; r < 16; r++) {
            int q = q0 + (r & 3) + 8 * (r >> 2) + 4 * half;
            lp[(hb + q) * NSLICE + ks] = lacc[r];
        }
    }
}

// ---- 6. phase 2: column weights w_j = sum_q exp(s)/l_q via 32x32x16 MFMA; 1/l inline ----
// grid (NSLICE=4 qs, 32 yg, 8 h); wave = 32 j x 1024-q strip
__global__ void __launch_bounds__(256) k_attn_w(
        const unsigned short* __restrict__ qpk, const unsigned short* __restrict__ kpk,
        const float* __restrict__ lp, float* __restrict__ wp) {
    __shared__ unsigned short smem[256 * 40];   // staged Q rows [Qh16|Ql16], stride 40
    __shared__ float rls[256];
    int tid = threadIdx.x;
    int qs = blockIdx.x, yg = blockIdx.y, h = blockIdx.z;
    size_t hb = (size_t)h * KSEL;
    int lane = tid & 63, w = tid >> 6;
    int n = lane & 31, half = lane >> 5;
    int j0 = yg * 128 + w * 32;
    const unsigned short* krow = kpk + (hb + j0 + n) * 32;
    bf16x8 aKh = *(const bf16x8*)(krow + half * 8);        // A[m=n=j-local][k]
    bf16x8 aKl = *(const bf16x8*)(krow + 16 + half * 8);
    float wacc[16];
    #pragma unroll
    for (int r = 0; r < 16; r++) wacc[r] = 0.f;
    for (int qc = 0; qc < 4; qc++) {
        __syncthreads();
        {
            int qrow = qs * 1024 + qc * 256 + tid;
            const float4* src = (const float4*)(qpk + (hb + qrow) * 32);
            float4 a0 = src[0], a1 = src[1], a2 = src[2], a3 = src[3];
            float4* dst = (float4*)&smem[tid * 40];
            dst[0] = a0; dst[1] = a1; dst[2] = a2; dst[3] = a3;
            float4 p = ((const float4*)lp)[hb + qrow];
            rls[tid] = 1.0f / ((p.x + p.y) + (p.z + p.w));
        }
        __syncthreads();
        #pragma unroll 2
        for (int t = 0; t < 8; t++) {
            const unsigned short* rowp = &smem[(t * 32 + n) * 40];
            bf16x8 bQh = *(const bf16x8*)(rowp + half * 8);     // B[k][n=q-local]
            bf16x8 bQl = *(const bf16x8*)(rowp + 16 + half * 8);
            f32x16 c = {0.f,0.f,0.f,0.f,0.f,0.f,0.f,0.f,0.f,0.f,0.f,0.f,0.f,0.f,0.f,0.f};
            c = __builtin_amdgcn_mfma_f32_32x32x16_bf16(aKh, bQh, c, 0, 0, 0);
            c = __builtin_amdgcn_mfma_f32_32x32x16_bf16(aKl, bQh, c, 0, 0, 0);
            c = __builtin_amdgcn_mfma_f32_32x32x16_bf16(aKh, bQl, c, 0, 0, 0);
            float rv = rls[t * 32 + n];
            #pragma unroll
            for (int r = 0; r < 16; r++) wacc[r] = fmaf(E2(c[r]), rv, wacc[r]);
        }
    }
    #pragma unroll
    for (int m = 1; m < 32; m <<= 1) {
        #pragma unroll
        for (int r = 0; r < 16; r++) wacc[r] += __shfl_xor(wacc[r], m);
    }
    if (n == 0) {
        #pragma unroll
        for (int r = 0; r < 16; r++) {
            int j = j0 + (r & 3) + 8 * (r >> 2) + 4 * half;
            wp[(hb + j) * NSLICE + qs] = wacc[r];
        }
    }
}

// ---- 7. pooled_av[d] += (1/K) sum_j w[h(d)][j] * v[j][d]  (32 j per block) ----
__global__ void __launch_bounds__(256) k_colsum(const float* __restrict__ wp, const float* __restrict__ vg,
                                                float* __restrict__ pav) {
    __shared__ float wl[NHEADS][32];
    __shared__ float red[128];
    int tid = threadIdx.x;
    int j0 = blockIdx.x * 32;
    {
        int h = tid >> 5, jl = tid & 31;
        float4 p = ((const float4*)wp)[(size_t)h * KSEL + j0 + jl];
        wl[h][jl] = (p.x + p.y) + (p.z + p.w);
    }
    __syncthreads();
    int d = tid & 127, g = tid >> 7;
    int h = d >> 4;
    float acc = 0.f;
    for (int jl = g * 16; jl < g * 16 + 16; jl++)
        acc = fmaf(wl[h][jl], vg[(size_t)(j0 + jl) * HIDDEN + d], acc);
    if (g == 1) red[d] = acc;
    __syncthreads();
    if (g == 0) atomicAdd(&pav[d], (acc + red[d]) * (1.0f / (float)KSEL));
}

// ---- 8. out-proj + pool MLP ----
__global__ void __launch_bounds__(256) k_final(const float* __restrict__ pav,
        const float* __restrict__ Wo, const float* __restrict__ bo,
        const float* __restrict__ W1, const float* __restrict__ b1,
        const float* __restrict__ W2, const float* __restrict__ b2,
        float* __restrict__ out) {
    __shared__ float sp[HIDDEN];
    __shared__ float st[OUTD];
    int t = threadIdx.x;
    if (t < HIDDEN) {
        float a = bo[t];
        for (int c = 0; c < HIDDEN; c++) a = fmaf(pav[c], Wo[c * HIDDEN + t], a);
        sp[t] = a;
    }
    __syncthreads();
    {
        float a = b1[t];
        for (int c = 0; c < HIDDEN; c++) a = fmaf(sp[c], W1[c * OUTD + t], a);
        st[t] = fmaxf(a, 0.f);
    }
    __syncthreads();
    {
        float o = b2[t];
        for (int c = 0; c < OUTD; c++) o = fmaf(st[c], W2[c * OUTD + t], o);
        out[t] = o;
    }
}

extern "C" void kernel_launch(void* const* d_in, const int* in_sizes, int n_in,
                              void* d_out, int out_size, void* d_ws, size_t ws_size,
                              hipStream_t stream) {
    (void)n_in; (void)out_size; (void)ws_size;
    const float* x   = (const float*)d_in[0];
    const float* pos = (const float*)d_in[1];
    const float* lig = (const float*)d_in[2];
    const float* Wn  = (const float*)d_in[3];
    const float* bn  = (const float*)d_in[4];
    const float* Wq  = (const float*)d_in[5];
    const float* bq  = (const float*)d_in[6];
    const float* Wk  = (const float*)d_in[7];
    const float* bk  = (const float*)d_in[8];
    const float* Wv  = (const float*)d_in[9];
    const float* bv  = (const float*)d_in[10];
    const float* Wo  = (const float*)d_in[11];
    const float* bo  = (const float*)d_in[12];
    const float* W1  = (const float*)d_in[13];
    const float* b1  = (const float*)d_in[14];
    const float* W2  = (const float*)d_in[15];
    const float* b2  = (const float*)d_in[16];
    int M = in_sizes[2] / 3;

    char* ws = (char*)d_ws;
    unsigned short* pa  = (unsigned short*)(ws + OFF_PA);
    unsigned short* pb  = (unsigned short*)(ws + OFF_PB);
    float*          sq  = (float*)(ws + OFF_SQ);
    float*          dl  = (float*)(ws + OFF_DL);
    int*            cnt = (int*)  (ws + OFF_CNT);
    unsigned int*   nfl = (unsigned int*)(ws + OFF_NFLAG);
    unsigned int*   flg = (unsigned int*)(ws + OFF_FLG);
    int*            sel = (int*)  (ws + OFF_SEL);
    unsigned short* qpk = (unsigned short*)(ws + OFF_QPK);
    unsigned short* kpk = (unsigned short*)(ws + OFF_KPK);
    float*          vg  = (float*)(ws + OFF_V);
    float*          lp  = (float*)(ws + OFF_LP);
    float*          wp  = (float*)(ws + OFF_WP);
    float*          pav = (float*)(ws + OFF_PAV);
    unsigned short* wsp = (unsigned short*)(ws + OFF_WSP);

    hipLaunchKernelGGL(k_prep,     dim3(67),       dim3(256),  0, stream, pos, lig, M, pa, pb, sq, dl, cnt, nfl, pav, Wq, Wk, Wv, wsp);
    hipLaunchKernelGGL(k_neighbor, dim3(128, 16),  dim3(256),  0, stream, pa, pb, cnt, flg, nfl);
    hipLaunchKernelGGL(k_fixup,    dim3(128),      dim3(256),  0, stream, pos, sq, flg, nfl, cnt);
    hipLaunchKernelGGL(k_select,   dim3(1),        dim3(1024), 0, stream, dl, cnt, sel);
    hipLaunchKernelGGL(k_qkv,      dim3(128, 3),   dim3(256),  0, stream, x, sel, Wn, bn, bq, bk, bv, wsp, qpk, kpk, vg);
    hipLaunchKernelGGL(k_attn_l,   dim3(4, 32, 8), dim3(256),  0, stream, qpk, kpk, lp);
    hipLaunchKernelGGL(k_attn_w,   dim3(4, 32, 8), dim3(256),  0, stream, qpk, kpk, lp, wp);
    hipLaunchKernelGGL(k_colsum,   dim3(KSEL/32),  dim3(256),  0, stream, wp, vg, pav);
    hipLaunchKernelGGL(k_final,    dim3(1),        dim3(256),  0, stream, pav, Wo, bo, W1, b1, W2, b2, (float*)d_out);
}